// Round 2
// baseline (1675.564 us; speedup 1.0000x reference)
//
#include <hip/hip_runtime.h>

// ---------------------------------------------------------------------------
// WindowAttention on MI355X (gfx950) — round 2.
// prep: weight transpose + bf16 cast into ws (unchanged).
// attn: ONE fused kernel per window (512 thr = 8 waves):
//   - x2 A-fragments loaded ONCE into registers (no per-head global re-reads)
//   - per head: kv GEMM -> LDS, q GEMM -> LDS, QK^T split over 8 waves
//     (cross-wave softmax via 1KB scratch in qhm pad cols), unnormalized-PV
//     accumulated in registers, rescaled by row-sum
//   - epilogue: o regs -> LDS (hi/lo bf16) -> proj 3-pass split-bf16 MFMA
//     -> final out write. proj kernel eliminated.
// Fragment layouts (m89/m91-verified): A/B: elem j -> [lane&15][quad*8+j]
// (B stored [N][K]); C/D: col=lane&15, row=quad*4+reg.
// ---------------------------------------------------------------------------

typedef __attribute__((ext_vector_type(8))) short bf16x8;
typedef __attribute__((ext_vector_type(4))) float f32x4;

#define MFMA16(a, b, c) __builtin_amdgcn_mfma_f32_16x16x32_bf16((a), (b), (c), 0, 0, 0)

// ws layout (ushort elements)
#define WS_QKVT  0        // [192][192]  qkv_w^T   bf16
#define WS_QKV2T 36864    // [384][192]  qkv2_w^T  bf16
#define WS_PROJH 110592   // [192][192]  proj_w^T  hi bf16
#define WS_PROJL 147456   // [192][192]  proj_w^T  lo bf16

#define SCALE_Q 0.17677669529663687f   // 32^-0.5

__device__ __forceinline__ unsigned short f2bf(float f) {
  unsigned int u = __float_as_uint(f);
  u += 0x7fffu + ((u >> 16) & 1u);     // round-to-nearest-even
  return (unsigned short)(u >> 16);
}
__device__ __forceinline__ float bf2f(unsigned short s) {
  return __uint_as_float(((unsigned int)s) << 16);
}
__device__ __forceinline__ bf16x8 cvt8(const float* __restrict__ p) {
  union { bf16x8 v; unsigned short s[8]; } U;
  float4 v0 = *(const float4*)p;
  float4 v1 = *(const float4*)(p + 4);
  U.s[0] = f2bf(v0.x); U.s[1] = f2bf(v0.y); U.s[2] = f2bf(v0.z); U.s[3] = f2bf(v0.w);
  U.s[4] = f2bf(v1.x); U.s[5] = f2bf(v1.y); U.s[6] = f2bf(v1.z); U.s[7] = f2bf(v1.w);
  return U.v;
}

// ---------------------------------------------------------------------------
__global__ void prep_kernel(const float* __restrict__ qkv_w,
                            const float* __restrict__ qkv2_w,
                            const float* __restrict__ proj_w,
                            unsigned short* __restrict__ ws) {
  int t = blockIdx.x * 256 + threadIdx.x;
  if (t < 36864) {                       // qkv_w (192x192)
    int k = t / 192, n = t % 192;
    ws[WS_QKVT + n * 192 + k] = f2bf(qkv_w[t]);
  } else if (t < 110592) {               // qkv2_w (192x384)
    int u = t - 36864;
    int k = u / 384, n = u % 384;
    ws[WS_QKV2T + n * 192 + k] = f2bf(qkv2_w[u]);
  } else if (t < 147456) {               // proj_w (192x192) hi/lo split
    int u = t - 110592;
    int k = u / 192, n = u % 192;
    float p = proj_w[u];
    unsigned short hi = f2bf(p);
    ws[WS_PROJH + n * 192 + k] = hi;
    ws[WS_PROJL + n * 192 + k] = f2bf(p - bf2f(hi));
  }
}

// ---------------------------------------------------------------------------
// kv tile: k,v head-slice GEMM for 16 rows of x2 (A-frags in registers).
// ---------------------------------------------------------------------------
__device__ __forceinline__ void kv_tile(const bf16x8* fr, int t, int h,
                                        const unsigned short* __restrict__ ws,
                                        const float* __restrict__ qkv2_b,
                                        unsigned short* ksm, unsigned short* vtm,
                                        int l16, int quad) {
  f32x4 a0{0.f,0.f,0.f,0.f}, a1{0.f,0.f,0.f,0.f};
  f32x4 a2{0.f,0.f,0.f,0.f}, a3{0.f,0.f,0.f,0.f};
  const unsigned short* wb = ws + WS_QKV2T + (h * 32 + l16) * 192;
#pragma unroll
  for (int kk = 0; kk < 6; ++kk) {
    const int k0 = kk * 32 + quad * 8;
    bf16x8 b0 = *(const bf16x8*)(wb + k0);
    bf16x8 b1 = *(const bf16x8*)(wb + 16 * 192 + k0);
    bf16x8 b2 = *(const bf16x8*)(wb + 192 * 192 + k0);
    bf16x8 b3 = *(const bf16x8*)(wb + 208 * 192 + k0);
    a0 = MFMA16(fr[kk], b0, a0);
    a1 = MFMA16(fr[kk], b1, a1);
    a2 = MFMA16(fr[kk], b2, a2);
    a3 = MFMA16(fr[kk], b3, a3);
  }
  const float bk0 = qkv2_b[h * 32 + l16];
  const float bk1 = qkv2_b[h * 32 + 16 + l16];
  const float bv0 = qkv2_b[192 + h * 32 + l16];
  const float bv1 = qkv2_b[192 + h * 32 + 16 + l16];
#pragma unroll
  for (int r = 0; r < 4; ++r) {
    const int row = t * 16 + quad * 4 + r;
    if (row < 196) {
      ksm[row * 40 + l16]      = f2bf(a0[r] + bk0);
      ksm[row * 40 + 16 + l16] = f2bf(a1[r] + bk1);
    }
    // rows up to 207 in-bounds of 232-stride; cols 196-207 finite garbage,
    // zeroed attn cols null them in PV.
    vtm[l16 * 232 + row]        = f2bf(a2[r] + bv0);
    vtm[(16 + l16) * 232 + row] = f2bf(a3[r] + bv1);
  }
}

// ---------------------------------------------------------------------------
// q tile: 16 rows of q = (x1 @ Wq_h + b) * SCALE  (A from global, L2-hot).
// ---------------------------------------------------------------------------
__device__ __forceinline__ void q_tile(int qt, int h,
                                       const float* __restrict__ x1b,
                                       const unsigned short* __restrict__ ws,
                                       const float* __restrict__ qkv_b,
                                       unsigned short* qhm, int l16, int quad) {
  const bf16x8 ZV = {0,0,0,0,0,0,0,0};
  f32x4 a0{0.f,0.f,0.f,0.f}, a1{0.f,0.f,0.f,0.f};
  const int m = qt * 16 + l16;
  const bool mv = (m < 49);
  const unsigned short* wq = ws + WS_QKVT + (h * 32 + l16) * 192;
#pragma unroll
  for (int kk = 0; kk < 6; ++kk) {
    const int k0 = kk * 32 + quad * 8;
    bf16x8 a = mv ? cvt8(x1b + m * 192 + k0) : ZV;
    a0 = MFMA16(a, *(const bf16x8*)(wq + k0), a0);
    a1 = MFMA16(a, *(const bf16x8*)(wq + 16 * 192 + k0), a1);
  }
  const float b0 = qkv_b[h * 32 + l16];
  const float b1 = qkv_b[h * 32 + 16 + l16];
#pragma unroll
  for (int r = 0; r < 4; ++r) {
    const int row = qt * 16 + quad * 4 + r;     // <= 63, in-bounds
    qhm[row * 40 + l16]      = f2bf((a0[r] + b0) * SCALE_Q);
    qhm[row * 40 + 16 + l16] = f2bf((a1[r] + b1) * SCALE_Q);
  }
}

// ---------------------------------------------------------------------------
// Fused attention + proj. One block per window, 8 waves.
// LDS 65,344 B:
//   ksm [196][40] @0        (15,680)  k, K-major in d
//   vtm [32][232] @15,680   (14,848)  v^T [d][pos]
//   atm [64][232] @30,528   (29,696)  unnormalized exp(logits)
//   qhm [64][40]  @60,224   ( 5,120)  q; cols 32-39 = softmax scratch
//     per row r: float[4] @ qhm+r*40+32 : {pmaxA, pmaxB, psumA, psumB}
//   oh/ol [64][200] bf16 overlay @0 / @25,600 (epilogue only)
// ---------------------------------------------------------------------------
__launch_bounds__(512, 4)
__global__ void attn_kernel(const float* __restrict__ x1,
                            const float* __restrict__ x2,
                            const float* __restrict__ qkv_b,
                            const float* __restrict__ qkv2_b,
                            const float* __restrict__ btab,   // [400][6]
                            const float* __restrict__ proj_b,
                            const unsigned short* __restrict__ ws,
                            float* __restrict__ out) {
  extern __shared__ char smem[];
  unsigned short* ksm = (unsigned short*)(smem);
  unsigned short* vtm = (unsigned short*)(smem + 15680);
  unsigned short* atm = (unsigned short*)(smem + 30528);
  unsigned short* qhm = (unsigned short*)(smem + 60224);
  unsigned short* oh  = (unsigned short*)(smem);          // epilogue overlay
  unsigned short* ol  = (unsigned short*)(smem + 25600);

  const int tid  = threadIdx.x;
  const int wave = tid >> 6;
  const int lane = tid & 63;
  const int l16  = lane & 15;
  const int quad = lane >> 4;
  const int b    = blockIdx.x;

  const float* x1b = x1 + (size_t)b * 9408;
  const float* x2b = x2 + (size_t)b * 37632;

  // ---- one-time x2 A-fragment load into registers -------------------------
  // kv-tile ownership: w0..w3:{w,w+8}  w4:{4,12}  w5..w7:{w}
  const bf16x8 ZV = {0,0,0,0,0,0,0,0};
  bf16x8 xf[12];
  const int t0 = wave;
  const int t1 = (wave < 4) ? wave + 8 : ((wave == 4) ? 12 : -1);
  {
    const int m0 = t0 * 16 + l16;
#pragma unroll
    for (int kk = 0; kk < 6; ++kk)
      xf[kk] = (m0 < 196) ? cvt8(x2b + m0 * 192 + kk * 32 + quad * 8) : ZV;
    if (t1 >= 0) {
      const int m1 = t1 * 16 + l16;
#pragma unroll
      for (int kk = 0; kk < 6; ++kk)
        xf[6 + kk] = (m1 < 196) ? cvt8(x2b + m1 * 192 + kk * 32 + quad * 8) : ZV;
    } else {
#pragma unroll
      for (int kk = 0; kk < 6; ++kk) xf[6 + kk] = ZV;
    }
  }

  // ---- zero atm + vtm (pads must stay 0 forever) --------------------------
  {
    int* z = (int*)(smem + 30528);
    for (int i = tid; i < 29696 / 4; i += 512) z[i] = 0;
    int* z2 = (int*)(smem + 15680);
    for (int i = tid; i < 14848 / 4; i += 512) z2[i] = 0;
  }

  // QK row/bias terms: mt2 = this wave's QK m-tile
  const int mt2 = (wave >= 4) ? wave - 4 : wave;
  const int ntb = (wave >= 4) ? 0 : 7;          // nt range base (A:0-6, B:7-12)
  const int g   = (wave >= 4) ? 0 : 1;          // scratch slot group
  int Pr[4];
#pragma unroll
  for (int r = 0; r < 4; ++r) {
    int i = mt2 * 16 + quad * 4 + r;
    if (i > 48) i = 48;
    int ih = i / 7, iw = i - 7 * ih;
    Pr[r] = ih * 20 + iw + 273;
  }
  // key-col bias terms for this wave's 7 nt tiles (hoisted across heads)
  int Qj[7];  bool Jv[7];
#pragma unroll
  for (int j = 0; j < 7; ++j) {
    const int nt = ntb + j;
    const int jc = nt * 16 + l16;
    Jv[j] = (nt <= 12) && (jc < 196);
    const int jcc = (jc < 196) ? jc : 195;
    const int jh = jcc / 14, jw = jcc - 14 * jh;
    Qj[j] = jh * 20 + jw;
  }

  __syncthreads();

  f32x4 o[6];

#pragma unroll
  for (int h = 0; h < 6; ++h) {
    // ================= phase 1: q/k/v head-slice GEMMs =====================
    kv_tile(xf, t0, h, ws, qkv2_b, ksm, vtm, l16, quad);
    if (t1 >= 0) kv_tile(xf + 6, t1, h, ws, qkv2_b, ksm, vtm, l16, quad);
    if (wave == 5) q_tile(0, h, x1b, ws, qkv_b, qhm, l16, quad);
    if (wave == 6) q_tile(1, h, x1b, ws, qkv_b, qhm, l16, quad);
    if (wave == 7) { q_tile(2, h, x1b, ws, qkv_b, qhm, l16, quad);
                     q_tile(3, h, x1b, ws, qkv_b, qhm, l16, quad); }
    __syncthreads();

    // ================= phase 2a: logits + bias + group max =================
    f32x4 lg[7];
    {
      bf16x8 aq = *(const bf16x8*)(qhm + (mt2 * 16 + l16) * 40 + quad * 8);
#pragma unroll
      for (int j = 0; j < 7; ++j) {
        const int nt = ntb + j;
        if (nt <= 12) {
          bf16x8 bb = *(const bf16x8*)(ksm + (nt * 16 + l16) * 40 + quad * 8);
          lg[j] = MFMA16(aq, bb, (f32x4{0.f, 0.f, 0.f, 0.f}));
          if (Jv[j]) {
#pragma unroll
            for (int r = 0; r < 4; ++r) lg[j][r] += btab[(Pr[r] - Qj[j]) * 6 + h];
          } else {
#pragma unroll
            for (int r = 0; r < 4; ++r) lg[j][r] = -1e30f;
          }
        } else {
#pragma unroll
          for (int r = 0; r < 4; ++r) lg[j][r] = -1e30f;
        }
      }
#pragma unroll
      for (int r = 0; r < 4; ++r) {
        float mx = lg[0][r];
#pragma unroll
        for (int j = 1; j < 7; ++j) mx = fmaxf(mx, lg[j][r]);
        mx = fmaxf(mx, __shfl_xor(mx, 1));
        mx = fmaxf(mx, __shfl_xor(mx, 2));
        mx = fmaxf(mx, __shfl_xor(mx, 4));
        mx = fmaxf(mx, __shfl_xor(mx, 8));
        if (l16 == 0) {
          const int row = mt2 * 16 + quad * 4 + r;
          *(float*)(qhm + row * 40 + 32 + 2 * g) = mx;
        }
      }
    }
    __syncthreads();

    // ================= phase 2b: exp, row-sum, unnormalized p -> atm =======
#pragma unroll
    for (int r = 0; r < 4; ++r) {
      const int row = mt2 * 16 + quad * 4 + r;
      const float* sc = (const float*)(qhm + row * 40 + 32);
      const float gm = fmaxf(sc[0], sc[1]);
      float s = 0.f;
#pragma unroll
      for (int j = 0; j < 7; ++j) {
        float p = __expf(lg[j][r] - gm);
        lg[j][r] = p;
        s += p;
      }
      s += __shfl_xor(s, 1);
      s += __shfl_xor(s, 2);
      s += __shfl_xor(s, 4);
      s += __shfl_xor(s, 8);
      if (l16 == 0) *(float*)(qhm + row * 40 + 36 + 2 * g) = s;
      if (row < 49) {
#pragma unroll
        for (int j = 0; j < 7; ++j) {
          const int jc = (ntb + j) * 16 + l16;   // <=223, in 232-stride; p=0 on pads
          atm[row * 232 + jc] = f2bf(lg[j][r]);
        }
      }
    }
    __syncthreads();

    // ================= phase 3: PV (unnormalized) + rescale ================
    {
      const int mt3 = wave >> 1, half = wave & 1;
      f32x4 t{0.f, 0.f, 0.f, 0.f};
#pragma unroll
      for (int kk = 0; kk < 7; ++kk) {
        const int k0 = kk * 32 + quad * 8;
        bf16x8 a = *(const bf16x8*)(atm + (mt3 * 16 + l16) * 232 + k0);
        bf16x8 v = *(const bf16x8*)(vtm + (half * 16 + l16) * 232 + k0);
        t = MFMA16(a, v, t);
      }
#pragma unroll
      for (int r = 0; r < 4; ++r) {
        const int row = mt3 * 16 + quad * 4 + r;
        const float* sc = (const float*)(qhm + row * 40 + 32);
        o[h][r] = t[r] * __frcp_rn(sc[2] + sc[3]);
      }
    }
    __syncthreads();   // protect ksm/vtm/qhm/atm for next head
  }

  // ================= epilogue: transpose o -> LDS, fused proj ==============
  {
    const int mt3 = wave >> 1, half = wave & 1;
#pragma unroll
    for (int h2 = 0; h2 < 6; ++h2)
#pragma unroll
      for (int r = 0; r < 4; ++r) {
        const int row = mt3 * 16 + quad * 4 + r;
        const int col = h2 * 32 + half * 16 + l16;
        const float v = o[h2][r];
        const unsigned short hi = f2bf(v);
        oh[row * 200 + col] = hi;
        ol[row * 200 + col] = f2bf(v - bf2f(hi));
      }
  }
  __syncthreads();
  {
    const int mtp = wave & 3;
    const int nb  = (wave < 4) ? 0 : 6;
    f32x4 pacc[6];
#pragma unroll
    for (int j = 0; j < 6; ++j) pacc[j] = f32x4{0.f, 0.f, 0.f, 0.f};
#pragma unroll
    for (int kk = 0; kk < 6; ++kk) {
      const int k0 = kk * 32 + quad * 8;
      bf16x8 ah = *(const bf16x8*)(oh + (mtp * 16 + l16) * 200 + k0);
      bf16x8 al = *(const bf16x8*)(ol + (mtp * 16 + l16) * 200 + k0);
#pragma unroll
      for (int j = 0; j < 6; ++j) {
        const unsigned short* bh = ws + WS_PROJH + ((nb + j) * 16 + l16) * 192 + k0;
        const unsigned short* bl = ws + WS_PROJL + ((nb + j) * 16 + l16) * 192 + k0;
        pacc[j] = MFMA16(ah, *(const bf16x8*)bh, pacc[j]);
        pacc[j] = MFMA16(ah, *(const bf16x8*)bl, pacc[j]);
        pacc[j] = MFMA16(al, *(const bf16x8*)bh, pacc[j]);
      }
    }
#pragma unroll
    for (int j = 0; j < 6; ++j) {
      const float pb = proj_b[(nb + j) * 16 + l16];
#pragma unroll
      for (int r = 0; r < 4; ++r) {
        const int row = mtp * 16 + quad * 4 + r;
        if (row < 49)
          out[(size_t)b * 9408 + row * 192 + (nb + j) * 16 + l16] = pacc[j][r] + pb;
      }
    }
  }
}

// ---------------------------------------------------------------------------
extern "C" void kernel_launch(void* const* d_in, const int* in_sizes, int n_in,
                              void* d_out, int out_size, void* d_ws, size_t ws_size,
                              hipStream_t stream) {
  const float* x1     = (const float*)d_in[0];
  const float* x2     = (const float*)d_in[1];
  const float* qkv_w  = (const float*)d_in[2];
  const float* qkv_b  = (const float*)d_in[3];
  const float* qkv2_w = (const float*)d_in[4];
  const float* qkv2_b = (const float*)d_in[5];
  const float* proj_w = (const float*)d_in[6];
  const float* proj_b = (const float*)d_in[7];
  const float* btab   = (const float*)d_in[8];
  unsigned short* ws  = (unsigned short*)d_ws;
  float* out          = (float*)d_out;
  (void)in_sizes; (void)n_in; (void)out_size; (void)ws_size;

  prep_kernel<<<dim3(576), dim3(256), 0, stream>>>(qkv_w, qkv2_w, proj_w, ws);
  attn_kernel<<<dim3(1024), dim3(512), 65344, stream>>>(x1, x2, qkv_b, qkv2_b,
                                                        btab, proj_b, ws, out);
}

// Round 3
// 1004.646 us; speedup vs baseline: 1.6678x; 1.6678x over previous
//
#include <hip/hip_runtime.h>

// ---------------------------------------------------------------------------
// WindowAttention on MI355X (gfx950) — round 3.
//   prep:  weight transpose + bf16 cast into ws.
//   qkv:   streaming GEMM, reads x1/x2 ONCE, writes q (scaled+bias), k
//          ([208][40] padded) and v^T ([32][232] padded) bf16 into ws.
//          v^T produced transposed for free by swapping MFMA operand roles.
//   attn:  per window: per head DMA k/v^T (31.5 KB) into LDS via
//          global_load_lds (issued early to overlap), q A-frags straight
//          from global, QK^T + cross-wave softmax + PV, fused split-bf16
//          proj epilogue. No register hoarding (round-2 spill post-mortem).
// Fragment layouts (m89/m91-verified): A/B: elem j -> [lane&15][quad*8+j]
// (operands K-major); C/D: col=lane&15, row=quad*4+reg.
// ---------------------------------------------------------------------------

typedef __attribute__((ext_vector_type(8))) short bf16x8;
typedef __attribute__((ext_vector_type(4))) float f32x4;

#define MFMA16(a, b, c) __builtin_amdgcn_mfma_f32_16x16x32_bf16((a), (b), (c), 0, 0, 0)

// weight-table layout (ushort offsets inside ws)
#define WS_QKVT  0        // [192][192] qkv_w^T
#define WS_QKV2T 36864    // [384][192] qkv2_w^T (rows 0-191 k, 192-383 v)
#define WS_PROJH 110592   // [192][192] proj_w^T hi
#define WS_PROJL 147456   // [192][192] proj_w^T lo
#define WT_USH   184320   // end of weight tables (368,640 bytes)

// per-window Y layout (ushort units)
#define Y1_STRIDE 12288   // [64][192] q, scaled+biased
#define WH_STRIDE 15744   // per window-head: k [208][40] then v^T [32][232]
#define VT_OFF    8320    // ushort offset of v^T inside a window-head record

#define SCALE_Q 0.17677669529663687f   // 32^-0.5

__device__ __forceinline__ unsigned short f2bf(float f) {
  unsigned int u = __float_as_uint(f);
  u += 0x7fffu + ((u >> 16) & 1u);     // round-to-nearest-even
  return (unsigned short)(u >> 16);
}
__device__ __forceinline__ float bf2f(unsigned short s) {
  return __uint_as_float(((unsigned int)s) << 16);
}
__device__ __forceinline__ bf16x8 cvt8(const float* __restrict__ p) {
  union { bf16x8 v; unsigned short s[8]; } U;
  float4 v0 = *(const float4*)p;
  float4 v1 = *(const float4*)(p + 4);
  U.s[0] = f2bf(v0.x); U.s[1] = f2bf(v0.y); U.s[2] = f2bf(v0.z); U.s[3] = f2bf(v0.w);
  U.s[4] = f2bf(v1.x); U.s[5] = f2bf(v1.y); U.s[6] = f2bf(v1.z); U.s[7] = f2bf(v1.w);
  return U.v;
}
// async global->LDS, 16B per lane; lds dest is wave-uniform base + lane*16
__device__ __forceinline__ void dma16(const unsigned short* g, unsigned short* l) {
  __builtin_amdgcn_global_load_lds(
      (const __attribute__((address_space(1))) unsigned int*)g,
      (__attribute__((address_space(3))) unsigned int*)l, 16, 0, 0);
}

// ---------------------------------------------------------------------------
__global__ void prep_kernel(const float* __restrict__ qkv_w,
                            const float* __restrict__ qkv2_w,
                            const float* __restrict__ proj_w,
                            unsigned short* __restrict__ ws) {
  int t = blockIdx.x * 256 + threadIdx.x;
  if (t < 36864) {
    int k = t / 192, n = t % 192;
    ws[WS_QKVT + n * 192 + k] = f2bf(qkv_w[t]);
  } else if (t < 110592) {
    int u = t - 36864;
    int k = u / 384, n = u % 384;
    ws[WS_QKV2T + n * 192 + k] = f2bf(qkv2_w[u]);
  } else if (t < 147456) {
    int u = t - 110592;
    int k = u / 192, n = u % 192;
    float p = proj_w[u];
    unsigned short hi = f2bf(p);
    ws[WS_PROJH + n * 192 + k] = hi;
    ws[WS_PROJL + n * 192 + k] = f2bf(p - bf2f(hi));
  }
}

// ---------------------------------------------------------------------------
// qkv producer. One block per window, 4 waves, no LDS, no barriers.
// 17 wave-tasks: 13 x2 pos-tiles (k + v^T), 4 x1 pos-tiles (q).
// ---------------------------------------------------------------------------
__launch_bounds__(256, 4)
__global__ void qkv_kernel(const float* __restrict__ x1,
                           const float* __restrict__ x2,
                           const float* __restrict__ qkv_b,
                           const float* __restrict__ qkv2_b,
                           const unsigned short* __restrict__ wt,
                           unsigned short* __restrict__ y1,
                           unsigned short* __restrict__ y2) {
  const int tid = threadIdx.x, wave = tid >> 6, lane = tid & 63;
  const int l16 = lane & 15, quad = lane >> 4;
  const int wl = blockIdx.x;
  const bf16x8 ZV = {0, 0, 0, 0, 0, 0, 0, 0};
  const float* x1b = x1 + (size_t)wl * 9408;
  const float* x2b = x2 + (size_t)wl * 37632;
  unsigned short* whbase = y2 + (size_t)wl * 6 * WH_STRIDE;
  unsigned short* y1b = y1 + (size_t)wl * Y1_STRIDE;

  for (int task = wave; task < 17; task += 4) {
    if (task < 13) {
      const int p0 = task * 16;
      const int m = p0 + l16;
      const bool mv = (m < 196);
      bf16x8 xf[6];
#pragma unroll
      for (int kk = 0; kk < 6; ++kk)
        xf[kk] = mv ? cvt8(x2b + m * 192 + kk * 32 + quad * 8) : ZV;
      // ---- k pass: A = x2 tile, B = Wk^T  (C: row=pos, col=kcol) ----------
#pragma unroll
      for (int j = 0; j < 12; ++j) {
        f32x4 acc{0.f, 0.f, 0.f, 0.f};
        const unsigned short* wb = wt + WS_QKV2T + (j * 16 + l16) * 192 + quad * 8;
#pragma unroll
        for (int kk = 0; kk < 6; ++kk)
          acc = MFMA16(xf[kk], *(const bf16x8*)(wb + kk * 32), acc);
        const float bia = qkv2_b[j * 16 + l16];
        unsigned short* kb = whbase + (j >> 1) * WH_STRIDE + (j & 1) * 16 + l16;
#pragma unroll
        for (int r = 0; r < 4; ++r)
          kb[(p0 + quad * 4 + r) * 40] = f2bf(acc[r] + bia);
      }
      // ---- v pass: A = Wv^T, B = x2 tile  (C: row=dim, col=pos -> v^T) ----
#pragma unroll
      for (int jb = 0; jb < 12; jb += 4) {
        f32x4 acc[4] = {{0,0,0,0},{0,0,0,0},{0,0,0,0},{0,0,0,0}};
#pragma unroll
        for (int kk = 0; kk < 6; ++kk) {
#pragma unroll
          for (int t = 0; t < 4; ++t) {
            const unsigned short* wa =
                wt + WS_QKV2T + (192 + (jb + t) * 16 + l16) * 192 + kk * 32 + quad * 8;
            acc[t] = MFMA16(*(const bf16x8*)wa, xf[kk], acc[t]);
          }
        }
#pragma unroll
        for (int t = 0; t < 4; ++t) {
          const int j = jb + t;
          const float4 vb = *(const float4*)(qkv2_b + 192 + j * 16 + quad * 4);
          unsigned short* vt = whbase + (j >> 1) * WH_STRIDE + VT_OFF
                             + ((j & 1) * 16 + quad * 4) * 232 + p0 + l16;
#pragma unroll
          for (int r = 0; r < 4; ++r)
            vt[r * 232] = f2bf(acc[t][r] + ((const float*)&vb)[r]);
        }
      }
    } else {
      // ---- q pass ---------------------------------------------------------
      const int p0 = (task - 13) * 16;
      const int m = p0 + l16;
      const bool mv = (m < 49);
      bf16x8 xf[6];
#pragma unroll
      for (int kk = 0; kk < 6; ++kk)
        xf[kk] = mv ? cvt8(x1b + m * 192 + kk * 32 + quad * 8) : ZV;
#pragma unroll
      for (int j = 0; j < 12; ++j) {
        f32x4 acc{0.f, 0.f, 0.f, 0.f};
        const unsigned short* wb = wt + WS_QKVT + (j * 16 + l16) * 192 + quad * 8;
#pragma unroll
        for (int kk = 0; kk < 6; ++kk)
          acc = MFMA16(xf[kk], *(const bf16x8*)(wb + kk * 32), acc);
        const float bia = qkv_b[j * 16 + l16];
#pragma unroll
        for (int r = 0; r < 4; ++r)
          y1b[(p0 + quad * 4 + r) * 192 + j * 16 + l16] =
              f2bf((acc[r] + bia) * SCALE_Q);
      }
    }
  }
}

// ---------------------------------------------------------------------------
// attention + fused proj. One block per window, 8 waves (512 thr).
// LDS 62,208 B:
//   ksm [208][40] @0       (16,640)  k, DMA target
//   vtm [32][232] @16,640  (14,848)  v^T, DMA target
//   atm [64][232] @31,488  (29,696)  exp(logits), cols 0..223 written/head
//   scr [64][4]f  @61,184  ( 1,024)  {maxA,maxB,sumA,sumB} per row
//   oh/ol [64][200] overlay @0 / @25,600 (epilogue only)
// ---------------------------------------------------------------------------
__device__ __forceinline__ void dma_region(const unsigned short* __restrict__ src,
                                           unsigned short* dst, int nslots, int tid) {
  for (int s = tid; s < nslots; s += 512)
    dma16(src + (size_t)s * 8, dst + (size_t)s * 8);
}

__launch_bounds__(512, 4)
__global__ void attn_kernel(const unsigned short* __restrict__ y1,
                            const unsigned short* __restrict__ y2,
                            const float* __restrict__ btab,   // [400][6]
                            const float* __restrict__ proj_b,
                            const unsigned short* __restrict__ wt,
                            float* __restrict__ out) {
  extern __shared__ char smem[];
  unsigned short* ksm = (unsigned short*)(smem);
  unsigned short* vtm = (unsigned short*)(smem + 16640);
  unsigned short* atm = (unsigned short*)(smem + 31488);
  float*          scr = (float*)(smem + 61184);
  unsigned short* oh  = (unsigned short*)(smem);
  unsigned short* ol  = (unsigned short*)(smem + 25600);

  const int tid = threadIdx.x, wave = tid >> 6, lane = tid & 63;
  const int l16 = lane & 15, quad = lane >> 4;
  const int wl = blockIdx.x;
  const unsigned short* y1w = y1 + (size_t)wl * Y1_STRIDE;
  const unsigned short* y2w = y2 + (size_t)wl * 6 * WH_STRIDE;

  const int mt2 = wave & 3;                  // QK m-tile
  const int ntb = (wave >= 4) ? 0 : 7;       // QK n-tile base (two groups)
  const int g   = (wave >= 4) ? 0 : 1;       // scratch slot
  int Pr[4];
#pragma unroll
  for (int r = 0; r < 4; ++r) {
    int i = mt2 * 16 + quad * 4 + r;
    if (i > 48) i = 48;
    int ih = i / 7, iw = i - 7 * ih;
    Pr[r] = ih * 20 + iw + 273;
  }
  int Qj[7]; bool Jv[7];
#pragma unroll
  for (int j = 0; j < 7; ++j) {
    const int nt = ntb + j;
    const int jc = nt * 16 + l16;
    Jv[j] = (nt <= 12) && (jc < 196);
    const int jcc = (jc < 196) ? jc : 195;
    const int jh = jcc / 14, jw = jcc - 14 * jh;
    Qj[j] = jh * 20 + jw;
  }

  // preload head 0
  dma_region(y2w, ksm, 1040, tid);
  dma_region(y2w + VT_OFF, vtm, 928, tid);

  f32x4 o[6];

#pragma unroll
  for (int h = 0; h < 6; ++h) {
    // q A-frag straight from global (issued before the DMA-drain barrier)
    bf16x8 aq = *(const bf16x8*)(y1w + (mt2 * 16 + l16) * 192 + h * 32 + quad * 8);
    __syncthreads();                         // DMA for head h complete

    // ---------------- 2a: logits + bias + group max ------------------------
    f32x4 lg[7];
#pragma unroll
    for (int j = 0; j < 7; ++j) {
      const int nt = ntb + j;
      if (nt <= 12) {
        bf16x8 bb = *(const bf16x8*)(ksm + (nt * 16 + l16) * 40 + quad * 8);
        lg[j] = MFMA16(aq, bb, (f32x4{0.f, 0.f, 0.f, 0.f}));
        if (Jv[j]) {
#pragma unroll
          for (int r = 0; r < 4; ++r) lg[j][r] += btab[(Pr[r] - Qj[j]) * 6 + h];
        } else {
#pragma unroll
          for (int r = 0; r < 4; ++r) lg[j][r] = -1e30f;
        }
      } else {
#pragma unroll
        for (int r = 0; r < 4; ++r) lg[j][r] = -1e30f;
      }
    }
#pragma unroll
    for (int r = 0; r < 4; ++r) {
      float mx = lg[0][r];
#pragma unroll
      for (int j = 1; j < 7; ++j) mx = fmaxf(mx, lg[j][r]);
      mx = fmaxf(mx, __shfl_xor(mx, 1));
      mx = fmaxf(mx, __shfl_xor(mx, 2));
      mx = fmaxf(mx, __shfl_xor(mx, 4));
      mx = fmaxf(mx, __shfl_xor(mx, 8));
      if (l16 == 0) scr[(mt2 * 16 + quad * 4 + r) * 4 + g] = mx;
    }
    __syncthreads();
    if (h < 5) dma_region(y2w + (h + 1) * WH_STRIDE, ksm, 1040, tid);  // ksm free

    // ---------------- 2b: exp, row-sum, p -> atm ---------------------------
#pragma unroll
    for (int r = 0; r < 4; ++r) {
      const int row = mt2 * 16 + quad * 4 + r;
      const float gm = fmaxf(scr[row * 4], scr[row * 4 + 1]);
      float s = 0.f;
#pragma unroll
      for (int j = 0; j < 7; ++j) {
        float p = __expf(lg[j][r] - gm);
        lg[j][r] = p;
        s += p;
      }
      s += __shfl_xor(s, 1);
      s += __shfl_xor(s, 2);
      s += __shfl_xor(s, 4);
      s += __shfl_xor(s, 8);
      if (l16 == 0) scr[row * 4 + 2 + g] = s;
#pragma unroll
      for (int j = 0; j < 7; ++j)
        atm[row * 232 + (ntb + j) * 16 + l16] = f2bf(lg[j][r]);
    }
    __syncthreads();

    // ---------------- 3: PV (unnormalized) + rescale -----------------------
    {
      const int mt3 = wave >> 1, half = wave & 1;
      f32x4 t{0.f, 0.f, 0.f, 0.f};
#pragma unroll
      for (int kk = 0; kk < 7; ++kk) {
        const int k0 = kk * 32 + quad * 8;
        bf16x8 a = *(const bf16x8*)(atm + (mt3 * 16 + l16) * 232 + k0);
        bf16x8 v = *(const bf16x8*)(vtm + (half * 16 + l16) * 232 + k0);
        t = MFMA16(a, v, t);
      }
#pragma unroll
      for (int r = 0; r < 4; ++r) {
        const int row = mt3 * 16 + quad * 4 + r;
        o[h][r] = t[r] * __frcp_rn(scr[row * 4 + 2] + scr[row * 4 + 3]);
      }
    }
    __syncthreads();
    if (h < 5) dma_region(y2w + (h + 1) * WH_STRIDE + VT_OFF, vtm, 928, tid);
  }

  // ---------------- epilogue: o -> LDS hi/lo, fused proj --------------------
  {
    const int mt3 = wave >> 1, half = wave & 1;
#pragma unroll
    for (int h2 = 0; h2 < 6; ++h2)
#pragma unroll
      for (int r = 0; r < 4; ++r) {
        const int row = mt3 * 16 + quad * 4 + r;
        const int col = h2 * 32 + half * 16 + l16;
        const float v = o[h2][r];
        const unsigned short hi = f2bf(v);
        oh[row * 200 + col] = hi;
        ol[row * 200 + col] = f2bf(v - bf2f(hi));
      }
  }
  __syncthreads();
  {
    const int mtp = wave & 3;
    const int nb = (wave < 4) ? 0 : 6;
    f32x4 pacc[6] = {{0,0,0,0},{0,0,0,0},{0,0,0,0},{0,0,0,0},{0,0,0,0},{0,0,0,0}};
#pragma unroll
    for (int kk = 0; kk < 6; ++kk) {
      const int k0 = kk * 32 + quad * 8;
      bf16x8 ah = *(const bf16x8*)(oh + (mtp * 16 + l16) * 200 + k0);
      bf16x8 al = *(const bf16x8*)(ol + (mtp * 16 + l16) * 200 + k0);
#pragma unroll
      for (int j = 0; j < 6; ++j) {
        bf16x8 bh = *(const bf16x8*)(wt + WS_PROJH + ((nb + j) * 16 + l16) * 192 + k0);
        bf16x8 bl = *(const bf16x8*)(wt + WS_PROJL + ((nb + j) * 16 + l16) * 192 + k0);
        pacc[j] = MFMA16(ah, bh, pacc[j]);
        pacc[j] = MFMA16(ah, bl, pacc[j]);
        pacc[j] = MFMA16(al, bh, pacc[j]);
      }
    }
#pragma unroll
    for (int j = 0; j < 6; ++j) {
      const float pb = proj_b[(nb + j) * 16 + l16];
#pragma unroll
      for (int r = 0; r < 4; ++r) {
        const int row = mtp * 16 + quad * 4 + r;
        if (row < 49)
          out[(size_t)wl * 9408 + row * 192 + (nb + j) * 16 + l16] = pacc[j][r] + pb;
      }
    }
  }
}

// ---------------------------------------------------------------------------
extern "C" void kernel_launch(void* const* d_in, const int* in_sizes, int n_in,
                              void* d_out, int out_size, void* d_ws, size_t ws_size,
                              hipStream_t stream) {
  const float* x1     = (const float*)d_in[0];
  const float* x2     = (const float*)d_in[1];
  const float* qkv_w  = (const float*)d_in[2];
  const float* qkv_b  = (const float*)d_in[3];
  const float* qkv2_w = (const float*)d_in[4];
  const float* qkv2_b = (const float*)d_in[5];
  const float* proj_w = (const float*)d_in[6];
  const float* proj_b = (const float*)d_in[7];
  const float* btab   = (const float*)d_in[8];
  unsigned short* wt  = (unsigned short*)d_ws;
  float* out          = (float*)d_out;
  (void)in_sizes; (void)n_in; (void)out_size;

  // chunk windows so Y1+Y2 fit in ws (ws_size is launch-invariant -> graph-safe)
  const long long per_w = 6LL * WH_STRIDE * 2 + Y1_STRIDE * 2;  // 213,504 B
  long long avail = (long long)ws_size - (long long)(WT_USH * 2);
  int W = (avail > 0) ? (int)(avail / per_w) : 1;
  if (W < 1) W = 1;
  if (W > 1024) W = 1024;
  unsigned short* y1 = wt + WT_USH;
  unsigned short* y2 = y1 + (size_t)W * Y1_STRIDE;

  prep_kernel<<<dim3(576), dim3(256), 0, stream>>>(qkv_w, qkv2_w, proj_w, wt);
  for (int c = 0; c < 1024; c += W) {
    int nw = 1024 - c;
    if (nw > W) nw = W;
    qkv_kernel<<<dim3(nw), dim3(256), 0, stream>>>(
        x1 + (size_t)c * 9408, x2 + (size_t)c * 37632, qkv_b, qkv2_b, wt, y1, y2);
    attn_kernel<<<dim3(nw), dim3(512), 62208, stream>>>(
        y1, y2, btab, proj_b, wt, out + (size_t)c * 9408);
  }
}